// Round 10
// baseline (62.105 us; speedup 1.0000x reference)
//
#include <hip/hip_runtime.h>
#include <math.h>

// Router: B=4, S=8192, D=1024, E=64, TOP_K=2 (all fp32)
// Output layout (fp32, concatenated flat):
//   [0,       65536)   top_k_probs   [4,8192,2]
//   [65536,   131072)  selected_experts (as float) [4,8192,2]
//   [131072,  2228224) router_logits [4,8192,64]
//
// R10: same fp32-exact 3-level bf16-split MFMA and LDS ring-3 staging as
// R9, but wave decomposition changed from [16 tok x 4 n x khalf] to
// [32 tok (2 M-tiles) x 2 n x khalf]:
//   - LDS reads halve: 6 ds_read_b128/wave/step (was 12). Lockstep-phase
//     arithmetic said LDS burst (768cyc) + MFMA burst (931cyc) serialize
//     per block-step; halving the LDS burst attacks the measured ~38us
//     floor (R7/R9 nulls ruled out DMA-latency explanations).
//   - MFMA/wave/step unchanged (2m x 2n x 6 = 24); same totals.
//   - Epilogue: khalf merge (areaA) then ng merge (areaB); all waves
//     stay alive through both barriers (no post-exit __syncthreads).
// Numerics bitwise-identical to R5-R9 (same 6 terms, same orders).

typedef __attribute__((ext_vector_type(8))) short bf16x8;
typedef __attribute__((ext_vector_type(4))) float f32x4;

static constexpr int TOKENS = 32768;
static constexpr int DDIM   = 1024;
static constexpr int NEXP   = 64;
static constexpr size_t OFF_EXP = 65536;
static constexpr size_t OFF_LOG = 131072;

// ---- W 3-level split + fragment-order permute (validated R4-R9) ----
__global__ void w_split3_kernel(const float* __restrict__ w,
                                short* __restrict__ w1,
                                short* __restrict__ w2,
                                short* __restrict__ w3) {
    int idx = blockIdx.x * blockDim.x + threadIdx.x;
    for (int i = idx; i < NEXP * DDIM; i += gridDim.x * blockDim.x) {
        int e = i >> 10, k = i & 1023;
        float f = w[i];
        unsigned u1 = __float_as_uint(f);
        float f1 = __uint_as_float(u1 & 0xffff0000u);
        float r1 = f - f1;
        unsigned u2 = __float_as_uint(r1);
        float f2 = __uint_as_float(u2 & 0xffff0000u);
        float r2 = r1 - f2;
        unsigned u3 = __float_as_uint(r2);
        int n = e >> 4, c = k >> 5;
        int lane = (e & 15) + ((k & 31) >> 3) * 16;
        int j = k & 7;
        size_t dst = ((size_t)(c * 4 + n) * 64 + lane) * 8 + j;
        w1[dst] = (short)(u1 >> 16);
        w2[dst] = (short)(u2 >> 16);
        w3[dst] = (short)(u3 >> 16);
    }
}

__device__ inline void split8(float4 a, float4 b,
                              bf16x8& o1, bf16x8& o2, bf16x8& o3) {
    float f[8] = {a.x, a.y, a.z, a.w, b.x, b.y, b.z, b.w};
#pragma unroll
    for (int j = 0; j < 8; ++j) {
        unsigned u1 = __float_as_uint(f[j]);
        float f1 = __uint_as_float(u1 & 0xffff0000u);
        float r1 = f[j] - f1;
        unsigned u2 = __float_as_uint(r1);
        float f2 = __uint_as_float(u2 & 0xffff0000u);
        float r2 = r1 - f2;
        o1[j] = (short)(u1 >> 16);
        o2[j] = (short)(u2 >> 16);
        o3[j] = (short)(__float_as_uint(r2) >> 16);
    }
}

typedef const __attribute__((address_space(1))) unsigned int* gas1_t;
typedef __attribute__((address_space(3))) unsigned int* las3_t;
__device__ inline void stage16(const void* g, void* l) {
    __builtin_amdgcn_global_load_lds((gas1_t)(uintptr_t)g,
                                     (las3_t)(uintptr_t)l, 16, 0, 0);
}

__global__ __launch_bounds__(512, 4)
void router_mfma_kernel(const float* __restrict__ h,
                        const short* __restrict__ w1,
                        const short* __restrict__ w2,
                        const short* __restrict__ w3,
                        float* __restrict__ out) {
    // ring of 3 staging bufs, 24 KB each, buf b at smem + b*24576.
    // Each buf: [khalf][arr][n] x 1KB segments (validated R6-R9).
    // Epilogue overlays: areaA at smem+24576 (bufs 1-2: last DMA step 14,
    // last read step 14; step 15 reads only buf0), areaB at smem+0
    // (written after first __syncthreads, when all step-15 reads done).
    __shared__ alignas(16) char smem[73728];
    const int tid   = threadIdx.x;
    const int lane  = tid & 63;
    const int wv    = tid >> 6;         // 0..7
    const int khalf = wv & 1;           // K half (0: k<512, 1: k>=512)
    const int ng    = (wv >> 1) & 1;    // n-tile pair: n = ng*2 + {0,1}
    const int mg    = wv >> 2;          // M group 0..1 (32 tokens each)
    const int token0 = blockIdx.x * 64 + mg * 32;   // M-tiles at +0, +16
    const int arow  = lane & 15;        // A-frag row (token within tile)
    const int ks    = lane >> 4;        // k slice within chunk

    const float* ap0 = h + (size_t)(token0 + arow) * DDIM + khalf * 512 + ks * 8;
    const float* ap1 = ap0 + (size_t)16 * DDIM;

    // staging assignment (verbatim R6-R9): seg = wv*3+i = (a*4+n)*2 + kh
    const short* warr[3] = {w1, w2, w3};
    const char* gsrc[3];
    int ldso[3];
#pragma unroll
    for (int i = 0; i < 3; ++i) {
        int seg = wv * 3 + i;
        int kh = seg & 1;
        int an = seg >> 1;              // 0..11
        int a = an >> 2, n = an & 3;
        gsrc[i] = (const char*)warr[a] + (size_t)(kh * 64 + n) * 1024 + lane * 16;
        ldso[i] = (kh * 12 + a * 4 + n) * 1024;
    }

#define STAGE(bb, cc)                                                      \
    {                                                                      \
        _Pragma("unroll")                                                  \
        for (int i = 0; i < 3; ++i)                                        \
            stage16(gsrc[i] + (size_t)(cc) * 4096,                         \
                    smem + (bb) * 24576 + ldso[i]);                        \
    }

    f32x4 acc[2][2];    // [m-tile][n-local]
#pragma unroll
    for (int m = 0; m < 2; ++m)
#pragma unroll
        for (int nl = 0; nl < 2; ++nl)
#pragma unroll
            for (int r = 0; r < 4; ++r) acc[m][nl][r] = 0.0f;

    // A register ring, depth 3: [slot][m-tile][half]; static indices only.
    float4 ring[3][2][2];

    // prologue: [DMA(0)x3, DMA(1)x3, A(0)x4, A(1)x4]; drain all (once).
    STAGE(0, 0);
    STAGE(1, 1);
    ring[0][0][0] = *reinterpret_cast<const float4*>(ap0);
    ring[0][0][1] = *reinterpret_cast<const float4*>(ap0 + 4);
    ring[0][1][0] = *reinterpret_cast<const float4*>(ap1);
    ring[0][1][1] = *reinterpret_cast<const float4*>(ap1 + 4);
    ring[1][0][0] = *reinterpret_cast<const float4*>(ap0 + 32);
    ring[1][0][1] = *reinterpret_cast<const float4*>(ap0 + 36);
    ring[1][1][0] = *reinterpret_cast<const float4*>(ap1 + 32);
    ring[1][1][1] = *reinterpret_cast<const float4*>(ap1 + 36);
    asm volatile("s_waitcnt vmcnt(0)" ::: "memory");
    __builtin_amdgcn_s_barrier();

#pragma unroll
    for (int t = 0; t < 16; ++t) {
        if (t + 2 < 16) {
            STAGE((t + 2) % 3, t + 2);              // DMA(t+2)x3
            ring[(t + 2) % 3][0][0] =
                *reinterpret_cast<const float4*>(ap0 + (t + 2) * 32);
            ring[(t + 2) % 3][0][1] =
                *reinterpret_cast<const float4*>(ap0 + (t + 2) * 32 + 4);
            ring[(t + 2) % 3][1][0] =
                *reinterpret_cast<const float4*>(ap1 + (t + 2) * 32);
            ring[(t + 2) % 3][1][1] =
                *reinterpret_cast<const float4*>(ap1 + (t + 2) * 32 + 4);
        }

        bf16x8 A1a, A2a, A3a, A1b, A2b, A3b;
        split8(ring[t % 3][0][0], ring[t % 3][0][1], A1a, A2a, A3a);
        split8(ring[t % 3][1][0], ring[t % 3][1][1], A1b, A2b, A3b);

        // wave reads only its 2 n-tiles: 6 ds_read_b128 (was 12)
        const char* wb = smem + (t % 3) * 24576 + khalf * 12288
                       + (ng * 2) * 1024 + lane * 16;
#pragma unroll
        for (int nl = 0; nl < 2; ++nl) {
            bf16x8 W1v = *reinterpret_cast<const bf16x8*>(wb + nl * 1024);
            bf16x8 W2v = *reinterpret_cast<const bf16x8*>(wb + nl * 1024 + 4096);
            bf16x8 W3v = *reinterpret_cast<const bf16x8*>(wb + nl * 1024 + 8192);
            f32x4 t0 = acc[0][nl];
            t0 = __builtin_amdgcn_mfma_f32_16x16x32_bf16(A3a, W1v, t0, 0, 0, 0);
            t0 = __builtin_amdgcn_mfma_f32_16x16x32_bf16(A1a, W3v, t0, 0, 0, 0);
            t0 = __builtin_amdgcn_mfma_f32_16x16x32_bf16(A2a, W2v, t0, 0, 0, 0);
            t0 = __builtin_amdgcn_mfma_f32_16x16x32_bf16(A2a, W1v, t0, 0, 0, 0);
            t0 = __builtin_amdgcn_mfma_f32_16x16x32_bf16(A1a, W2v, t0, 0, 0, 0);
            t0 = __builtin_amdgcn_mfma_f32_16x16x32_bf16(A1a, W1v, t0, 0, 0, 0);
            acc[0][nl] = t0;
            f32x4 t1 = acc[1][nl];
            t1 = __builtin_amdgcn_mfma_f32_16x16x32_bf16(A3b, W1v, t1, 0, 0, 0);
            t1 = __builtin_amdgcn_mfma_f32_16x16x32_bf16(A1b, W3v, t1, 0, 0, 0);
            t1 = __builtin_amdgcn_mfma_f32_16x16x32_bf16(A2b, W2v, t1, 0, 0, 0);
            t1 = __builtin_amdgcn_mfma_f32_16x16x32_bf16(A2b, W1v, t1, 0, 0, 0);
            t1 = __builtin_amdgcn_mfma_f32_16x16x32_bf16(A1b, W2v, t1, 0, 0, 0);
            t1 = __builtin_amdgcn_mfma_f32_16x16x32_bf16(A1b, W1v, t1, 0, 0, 0);
            acc[1][nl] = t1;
        }

        if (t <= 13) {
            // queue (<=14): step-(t+1) batch [DMA x3 + A x4] is oldest in any
            // within-batch order; vmcnt(7) drains through all of it.
            asm volatile("s_waitcnt vmcnt(7)" ::: "memory");
            __builtin_amdgcn_s_barrier();
        } else if (t == 14) {
            asm volatile("s_waitcnt vmcnt(0)" ::: "memory");
            __builtin_amdgcn_s_barrier();
        }
    }

    // ---- merge 1: K-halves via areaA (smem+24576), 16 floats/lane pad 17 --
    if (khalf == 1) {
        float* cA = (float*)(smem + 24576)
                  + (size_t)((mg * 2 + ng) * 64 + lane) * 17;
#pragma unroll
        for (int m = 0; m < 2; ++m)
#pragma unroll
            for (int nl = 0; nl < 2; ++nl)
#pragma unroll
                for (int r = 0; r < 4; ++r)
                    cA[(m * 2 + nl) * 4 + r] = acc[m][nl][r];
    }
    __syncthreads();
    if (khalf == 0) {
        const float* cA = (const float*)(smem + 24576)
                        + (size_t)((mg * 2 + ng) * 64 + lane) * 17;
#pragma unroll
        for (int m = 0; m < 2; ++m)
#pragma unroll
            for (int nl = 0; nl < 2; ++nl)
#pragma unroll
                for (int r = 0; r < 4; ++r)
                    acc[m][nl][r] += cA[(m * 2 + nl) * 4 + r];
        // ---- merge 2: ng=1 publishes via areaB (smem+0) ----
        if (ng == 1) {
            float* cB = (float*)smem + (size_t)(mg * 64 + lane) * 17;
#pragma unroll
            for (int m = 0; m < 2; ++m)
#pragma unroll
                for (int nl = 0; nl < 2; ++nl)
#pragma unroll
                    for (int r = 0; r < 4; ++r)
                        cB[(m * 2 + nl) * 4 + r] = acc[m][nl][r];
        }
    }
    __syncthreads();
    if (khalf != 0 || ng != 0) return;

    // surviving waves: 2 per block; assemble full acc4[m][n][r]
    f32x4 acc4[2][4];
    {
        const float* cB = (const float*)smem + (size_t)(mg * 64 + lane) * 17;
#pragma unroll
        for (int m = 0; m < 2; ++m)
#pragma unroll
            for (int nl = 0; nl < 2; ++nl) {
                acc4[m][nl] = acc[m][nl];
#pragma unroll
                for (int r = 0; r < 4; ++r)
                    acc4[m][2 + nl][r] = cB[(m * 2 + nl) * 4 + r];
            }
    }

    const int rbase = (lane >> 4) * 4;   // C/D row group (token offset)
    const int col   = lane & 15;         // C/D col (expert within tile)

    // ---- logits ----
#pragma unroll
    for (int m = 0; m < 2; ++m)
#pragma unroll
        for (int n = 0; n < 4; ++n)
#pragma unroll
            for (int r = 0; r < 4; ++r)
                out[OFF_LOG + (size_t)(token0 + m * 16 + rbase + r) * NEXP
                    + n * 16 + col] = acc4[m][n][r];

    // ---- softmax + top-2 per token (16-lane groups, xor 1,2,4,8) ----
#pragma unroll
    for (int m = 0; m < 2; ++m)
#pragma unroll
    for (int r = 0; r < 4; ++r) {
        const int token = token0 + m * 16 + rbase + r;
        float mx = fmaxf(fmaxf(acc4[m][0][r], acc4[m][1][r]),
                         fmaxf(acc4[m][2][r], acc4[m][3][r]));
#pragma unroll
        for (int d = 1; d <= 8; d <<= 1) mx = fmaxf(mx, __shfl_xor(mx, d, 64));

        float p[4];
        float s = 0.0f;
#pragma unroll
        for (int n = 0; n < 4; ++n) { p[n] = expf(acc4[m][n][r] - mx); s += p[n]; }
#pragma unroll
        for (int d = 1; d <= 8; d <<= 1) s += __shfl_xor(s, d, 64);

        // local top-2 over n (expert = n*16 + col, ascending; '>' keeps lower)
        float v1 = -INFINITY, v2 = -INFINITY;
        int   i1 = NEXP,      i2 = NEXP;
#pragma unroll
        for (int n = 0; n < 4; ++n) {
            float v = p[n];
            int   ei = n * 16 + col;
            if (v > v1)      { v2 = v1; i2 = i1; v1 = v; i1 = ei; }
            else if (v > v2) { v2 = v;  i2 = ei; }
        }

        // merge across the 16 lanes of the group
#pragma unroll
        for (int d = 1; d <= 8; d <<= 1) {
            float ov1 = __shfl_xor(v1, d, 64);
            float ov2 = __shfl_xor(v2, d, 64);
            int   oi1 = __shfl_xor(i1, d, 64);
            int   oi2 = __shfl_xor(i2, d, 64);
            bool ofirst = (ov1 > v1) || (ov1 == v1 && oi1 < i1);
            float n1, n2; int ni1, ni2;
            if (ofirst) {
                n1 = ov1; ni1 = oi1;
                bool sec = (v1 > ov2) || (v1 == ov2 && i1 < oi2);
                n2 = sec ? v1 : ov2; ni2 = sec ? i1 : oi2;
            } else {
                n1 = v1; ni1 = i1;
                bool sec = (ov1 > v2) || (ov1 == v2 && oi1 < i2);
                n2 = sec ? ov1 : v2; ni2 = sec ? oi1 : i2;
            }
            v1 = n1; i1 = ni1; v2 = n2; i2 = ni2;
        }

        if (col == 0) {
            float t1 = v1 / s;
            float t2 = v2 / s;
            float dn = t1 + t2 + 1e-8f;
            float2 pr; pr.x = t1 / dn; pr.y = t2 / dn;
            *reinterpret_cast<float2*>(out + (size_t)token * 2) = pr;
            float2 ex; ex.x = (float)i1; ex.y = (float)i2;
            *reinterpret_cast<float2*>(out + OFF_EXP + (size_t)token * 2) = ex;
        }
    }
#undef STAGE
}

extern "C" void kernel_launch(void* const* d_in, const int* in_sizes, int n_in,
                              void* d_out, int out_size, void* d_ws, size_t ws_size,
                              hipStream_t stream) {
    const float* h = (const float*)d_in[0];
    const float* w = (const float*)d_in[1];
    float* out = (float*)d_out;
    // d_ws: W1 | W2 | W3, each 65536 shorts = 384 KiB total
    short* w1 = (short*)d_ws;
    short* w2 = w1 + (size_t)NEXP * DDIM;
    short* w3 = w2 + (size_t)NEXP * DDIM;
    hipLaunchKernelGGL(w_split3_kernel, dim3(128), dim3(256), 0, stream, w, w1, w2, w3);
    hipLaunchKernelGGL(router_mfma_kernel, dim3(TOKENS / 64), dim3(512), 0, stream,
                       h, w1, w2, w3, out);
}

// Round 11
// 47.093 us; speedup vs baseline: 1.3188x; 1.3188x over previous
//
#include <hip/hip_runtime.h>
#include <math.h>

// Router: B=4, S=8192, D=1024, E=64, TOP_K=2 (all fp32)
// Output layout (fp32, concatenated flat):
//   [0,       65536)   top_k_probs   [4,8192,2]
//   [65536,   131072)  selected_experts (as float) [4,8192,2]
//   [131072,  2228224) router_logits [4,8192,64]
//
// R11: fp32-exact 3-level bf16-split MFMA (validated R5-R10), BK=64:
//  - Block = 8 waves = 8 M-groups, 128 tokens; each wave owns 16 tokens x
//    64 experts x FULL K. Grid 256, 2 blocks/CU, 4 waves/SIMD (preserved).
//  - Per step stages chunks {t, 16+t} (24 KB, ring-2 = 48 KB LDS);
//    48 MFMA + 24 ds_read per wave-step -> per-CU block-steps halve
//    (32 -> 16), amortizing the measured ~900cyc/barrier convoy overhead.
//  - khalf LDS-combine epilogue ELIMINATED: two register accumulator sets
//    (accA: chunks 0..15, accB: 16..31, same per-half order, same 6-term
//    order, final accA+accB = old combine's add order) keep numerics
//    bitwise-identical to R5-R10 while each wave ends with full logits.
//  - R8/R10 lesson: occupancy and VGPR preserved (~110 regs, ring-2 only).

typedef __attribute__((ext_vector_type(8))) short bf16x8;
typedef __attribute__((ext_vector_type(4))) float f32x4;

static constexpr int TOKENS = 32768;
static constexpr int DDIM   = 1024;
static constexpr int NEXP   = 64;
static constexpr size_t OFF_EXP = 65536;
static constexpr size_t OFF_LOG = 131072;

// ---- W 3-level split + fragment-order permute (validated R4-R10) ----
__global__ void w_split3_kernel(const float* __restrict__ w,
                                short* __restrict__ w1,
                                short* __restrict__ w2,
                                short* __restrict__ w3) {
    int idx = blockIdx.x * blockDim.x + threadIdx.x;
    for (int i = idx; i < NEXP * DDIM; i += gridDim.x * blockDim.x) {
        int e = i >> 10, k = i & 1023;
        float f = w[i];
        unsigned u1 = __float_as_uint(f);
        float f1 = __uint_as_float(u1 & 0xffff0000u);
        float r1 = f - f1;
        unsigned u2 = __float_as_uint(r1);
        float f2 = __uint_as_float(u2 & 0xffff0000u);
        float r2 = r1 - f2;
        unsigned u3 = __float_as_uint(r2);
        int n = e >> 4, c = k >> 5;
        int lane = (e & 15) + ((k & 31) >> 3) * 16;
        int j = k & 7;
        size_t dst = ((size_t)(c * 4 + n) * 64 + lane) * 8 + j;
        w1[dst] = (short)(u1 >> 16);
        w2[dst] = (short)(u2 >> 16);
        w3[dst] = (short)(u3 >> 16);
    }
}

__device__ inline void split8(float4 a, float4 b,
                              bf16x8& o1, bf16x8& o2, bf16x8& o3) {
    float f[8] = {a.x, a.y, a.z, a.w, b.x, b.y, b.z, b.w};
#pragma unroll
    for (int j = 0; j < 8; ++j) {
        unsigned u1 = __float_as_uint(f[j]);
        float f1 = __uint_as_float(u1 & 0xffff0000u);
        float r1 = f[j] - f1;
        unsigned u2 = __float_as_uint(r1);
        float f2 = __uint_as_float(u2 & 0xffff0000u);
        float r2 = r1 - f2;
        o1[j] = (short)(u1 >> 16);
        o2[j] = (short)(u2 >> 16);
        o3[j] = (short)(__float_as_uint(r2) >> 16);
    }
}

typedef const __attribute__((address_space(1))) unsigned int* gas1_t;
typedef __attribute__((address_space(3))) unsigned int* las3_t;
__device__ inline void stage16(const void* g, void* l) {
    __builtin_amdgcn_global_load_lds((gas1_t)(uintptr_t)g,
                                     (las3_t)(uintptr_t)l, 16, 0, 0);
}

__global__ __launch_bounds__(512, 4)
void router_mfma_kernel(const float* __restrict__ h,
                        const short* __restrict__ w1,
                        const short* __restrict__ w2,
                        const short* __restrict__ w3,
                        float* __restrict__ out) {
    // 2 staging bufs x 24 KB. Buf layout: [kc][arr][n] x 1KB (kc = K-half
    // of the step pair: chunk t (kc=0) and chunk 16+t (kc=1)).
    __shared__ alignas(16) char smem[49152];
    const int tid   = threadIdx.x;
    const int lane  = tid & 63;
    const int wv    = tid >> 6;         // 0..7 = M group
    const int token0 = blockIdx.x * 128 + wv * 16;
    const int arow  = lane & 15;        // A-frag row (token within tile)
    const int ks    = lane >> 4;        // k slice within chunk

    const float* ap = h + (size_t)(token0 + arow) * DDIM + ks * 8;

    // staging: 24 segs/step, 3 per wave. seg = wv*3+i = kc*12 + a*4 + n.
    // src bytes for (c=kc*16+t, n): (c*4+n)*1024 + lane*16
    //   = kc*65536 + n*1024 + lane*16 + t*4096.
    const short* warr[3] = {w1, w2, w3};
    const char* gsrc[3];
    int ldso[3];
#pragma unroll
    for (int i = 0; i < 3; ++i) {
        int seg = wv * 3 + i;
        int kc = seg / 12;
        int rem = seg % 12;
        int a = rem >> 2, n = rem & 3;
        gsrc[i] = (const char*)warr[a] + (size_t)kc * 65536 + n * 1024 + lane * 16;
        ldso[i] = (kc * 12 + a * 4 + n) * 1024;
    }

#define STAGE(bb, tt)                                                      \
    {                                                                      \
        _Pragma("unroll")                                                  \
        for (int i = 0; i < 3; ++i)                                        \
            stage16(gsrc[i] + (size_t)(tt) * 4096,                         \
                    smem + (bb) * 24576 + ldso[i]);                        \
    }

    // Two accumulator sets: accA = chunks 0..15, accB = chunks 16..31.
    // Final accA+accB reproduces R6's khalf-combine add order exactly.
    f32x4 accA[4], accB[4];
#pragma unroll
    for (int n = 0; n < 4; ++n)
#pragma unroll
        for (int r = 0; r < 4; ++r) { accA[n][r] = 0.0f; accB[n][r] = 0.0f; }

    // A ping-pong: [slot][kc][lo/hi]; static indices only.
    float4 ring[2][2][2];

    // prologue: [DMA(0)x3, A(0)x4] -> retire DMA(0): vmcnt(4)
    STAGE(0, 0);
    ring[0][0][0] = *reinterpret_cast<const float4*>(ap);
    ring[0][0][1] = *reinterpret_cast<const float4*>(ap + 4);
    ring[0][1][0] = *reinterpret_cast<const float4*>(ap + 512);
    ring[0][1][1] = *reinterpret_cast<const float4*>(ap + 516);
    asm volatile("s_waitcnt vmcnt(4)" ::: "memory");
    __builtin_amdgcn_s_barrier();

#pragma unroll
    for (int t = 0; t < 16; ++t) {
        const int b = t & 1;
        if (t + 1 < 16) {
            STAGE(b ^ 1, t + 1);                    // DMA(t+1) x3
            ring[b ^ 1][0][0] =
                *reinterpret_cast<const float4*>(ap + (t + 1) * 32);
            ring[b ^ 1][0][1] =
                *reinterpret_cast<const float4*>(ap + (t + 1) * 32 + 4);
            ring[b ^ 1][1][0] =
                *reinterpret_cast<const float4*>(ap + 512 + (t + 1) * 32);
            ring[b ^ 1][1][1] =
                *reinterpret_cast<const float4*>(ap + 512 + (t + 1) * 32 + 4);
        }

        bf16x8 A1a, A2a, A3a, A1b, A2b, A3b;
        split8(ring[b][0][0], ring[b][0][1], A1a, A2a, A3a);   // chunk t
        split8(ring[b][1][0], ring[b][1][1], A1b, A2b, A3b);   // chunk 16+t

        const char* wb0 = smem + b * 24576 + lane * 16;         // kc=0
        const char* wb1 = wb0 + 12288;                          // kc=1
#pragma unroll
        for (int n = 0; n < 4; ++n) {
            bf16x8 W1v = *reinterpret_cast<const bf16x8*>(wb0 + n * 1024);
            bf16x8 W2v = *reinterpret_cast<const bf16x8*>(wb0 + n * 1024 + 4096);
            bf16x8 W3v = *reinterpret_cast<const bf16x8*>(wb0 + n * 1024 + 8192);
            f32x4 t0 = accA[n];
            t0 = __builtin_amdgcn_mfma_f32_16x16x32_bf16(A3a, W1v, t0, 0, 0, 0);
            t0 = __builtin_amdgcn_mfma_f32_16x16x32_bf16(A1a, W3v, t0, 0, 0, 0);
            t0 = __builtin_amdgcn_mfma_f32_16x16x32_bf16(A2a, W2v, t0, 0, 0, 0);
            t0 = __builtin_amdgcn_mfma_f32_16x16x32_bf16(A2a, W1v, t0, 0, 0, 0);
            t0 = __builtin_amdgcn_mfma_f32_16x16x32_bf16(A1a, W2v, t0, 0, 0, 0);
            t0 = __builtin_amdgcn_mfma_f32_16x16x32_bf16(A1a, W1v, t0, 0, 0, 0);
            accA[n] = t0;
            bf16x8 X1v = *reinterpret_cast<const bf16x8*>(wb1 + n * 1024);
            bf16x8 X2v = *reinterpret_cast<const bf16x8*>(wb1 + n * 1024 + 4096);
            bf16x8 X3v = *reinterpret_cast<const bf16x8*>(wb1 + n * 1024 + 8192);
            f32x4 t1 = accB[n];
            t1 = __builtin_amdgcn_mfma_f32_16x16x32_bf16(A3b, X1v, t1, 0, 0, 0);
            t1 = __builtin_amdgcn_mfma_f32_16x16x32_bf16(A1b, X3v, t1, 0, 0, 0);
            t1 = __builtin_amdgcn_mfma_f32_16x16x32_bf16(A2b, X2v, t1, 0, 0, 0);
            t1 = __builtin_amdgcn_mfma_f32_16x16x32_bf16(A2b, X1v, t1, 0, 0, 0);
            t1 = __builtin_amdgcn_mfma_f32_16x16x32_bf16(A1b, X2v, t1, 0, 0, 0);
            t1 = __builtin_amdgcn_mfma_f32_16x16x32_bf16(A1b, X1v, t1, 0, 0, 0);
            accB[n] = t1;
        }

        if (t + 1 < 16) {
            // queue: [DMA(t+1)x3, A(t+1)x4] -> vmcnt(4) retires the DMAs
            asm volatile("s_waitcnt vmcnt(4)" ::: "memory");
            __builtin_amdgcn_s_barrier();
        }
    }

    // ---- combine halves in registers (same add order as R6's LDS merge) --
    f32x4 acc[4];
#pragma unroll
    for (int n = 0; n < 4; ++n)
#pragma unroll
        for (int r = 0; r < 4; ++r) acc[n][r] = accA[n][r] + accB[n][r];

    const int rbase = (lane >> 4) * 4;   // C/D row group (token offset)
    const int col   = lane & 15;         // C/D col (expert within tile)

    // ---- logits ----
#pragma unroll
    for (int n = 0; n < 4; ++n)
#pragma unroll
        for (int r = 0; r < 4; ++r)
            out[OFF_LOG + (size_t)(token0 + rbase + r) * NEXP + n * 16 + col]
                = acc[n][r];

    // ---- softmax + top-2 per token (16-lane groups, xor 1,2,4,8) ----
#pragma unroll
    for (int r = 0; r < 4; ++r) {
        const int token = token0 + rbase + r;
        float mx = fmaxf(fmaxf(acc[0][r], acc[1][r]),
                         fmaxf(acc[2][r], acc[3][r]));
#pragma unroll
        for (int d = 1; d <= 8; d <<= 1) mx = fmaxf(mx, __shfl_xor(mx, d, 64));

        float p[4];
        float s = 0.0f;
#pragma unroll
        for (int n = 0; n < 4; ++n) { p[n] = expf(acc[n][r] - mx); s += p[n]; }
#pragma unroll
        for (int d = 1; d <= 8; d <<= 1) s += __shfl_xor(s, d, 64);

        // local top-2 over n (expert = n*16 + col, ascending; '>' keeps lower)
        float v1 = -INFINITY, v2 = -INFINITY;
        int   i1 = NEXP,      i2 = NEXP;
#pragma unroll
        for (int n = 0; n < 4; ++n) {
            float v = p[n];
            int   ei = n * 16 + col;
            if (v > v1)      { v2 = v1; i2 = i1; v1 = v; i1 = ei; }
            else if (v > v2) { v2 = v;  i2 = ei; }
        }

        // merge across the 16 lanes of the group
#pragma unroll
        for (int d = 1; d <= 8; d <<= 1) {
            float ov1 = __shfl_xor(v1, d, 64);
            float ov2 = __shfl_xor(v2, d, 64);
            int   oi1 = __shfl_xor(i1, d, 64);
            int   oi2 = __shfl_xor(i2, d, 64);
            bool ofirst = (ov1 > v1) || (ov1 == v1 && oi1 < i1);
            float n1, n2; int ni1, ni2;
            if (ofirst) {
                n1 = ov1; ni1 = oi1;
                bool sec = (v1 > ov2) || (v1 == ov2 && i1 < oi2);
                n2 = sec ? v1 : ov2; ni2 = sec ? i1 : oi2;
            } else {
                n1 = v1; ni1 = i1;
                bool sec = (ov1 > v2) || (ov1 == v2 && oi1 < i2);
                n2 = sec ? ov1 : v2; ni2 = sec ? oi1 : i2;
            }
            v1 = n1; i1 = ni1; v2 = n2; i2 = ni2;
        }

        if (col == 0) {
            float t1 = v1 / s;
            float t2 = v2 / s;
            float dn = t1 + t2 + 1e-8f;
            float2 pr; pr.x = t1 / dn; pr.y = t2 / dn;
            *reinterpret_cast<float2*>(out + (size_t)token * 2) = pr;
            float2 ex; ex.x = (float)i1; ex.y = (float)i2;
            *reinterpret_cast<float2*>(out + OFF_EXP + (size_t)token * 2) = ex;
        }
    }
#undef STAGE
}

extern "C" void kernel_launch(void* const* d_in, const int* in_sizes, int n_in,
                              void* d_out, int out_size, void* d_ws, size_t ws_size,
                              hipStream_t stream) {
    const float* h = (const float*)d_in[0];
    const float* w = (const float*)d_in[1];
    float* out = (float*)d_out;
    // d_ws: W1 | W2 | W3, each 65536 shorts = 384 KiB total
    short* w1 = (short*)d_ws;
    short* w2 = w1 + (size_t)NEXP * DDIM;
    short* w3 = w2 + (size_t)NEXP * DDIM;
    hipLaunchKernelGGL(w_split3_kernel, dim3(128), dim3(256), 0, stream, w, w1, w2, w3);
    hipLaunchKernelGGL(router_mfma_kernel, dim3(TOKENS / 128), dim3(512), 0, stream,
                       h, w1, w2, w3, out);
}